// Round 15
// baseline (138.624 us; speedup 1.0000x reference)
//
#include <hip/hip_runtime.h>
#include <hip/hip_bf16.h>
#include <math.h>

#define IMG 128
#define PATCH 16
#define L 64
#define D 256
#define DIN 512
#define DH 64
#define H 8
#define NSTATE 64
#define DCONV 4
#define DEPTH 2
#define NCLS 1000
#define BATCH 16
#define DINPROJ 1160   // 2*DIN + 2*N + H
#define CDIM 640       // DIN + 2*N
#define EPS 1e-6f
#define SLAB (BATCH * L * D)   // 262144

typedef __attribute__((ext_vector_type(8))) short short8;
typedef __attribute__((ext_vector_type(4))) float f32x4;
typedef __attribute__((ext_vector_type(4))) unsigned short us4;
typedef unsigned short ushort_t;

__device__ __forceinline__ int snake_tok(int s){
    int r = s >> 3, c = s & 7;
    return (r & 1) ? (r * 8 + (7 - c)) : (r * 8 + c);
}
__device__ __forceinline__ float silu_f(float x){ return x / (1.f + expf(-x)); }
__device__ __forceinline__ float softplus_f(float x){ return x > 20.f ? x : log1pf(expf(x)); }
__device__ __forceinline__ ushort_t f2b(float f){
    __hip_bfloat16 h = __float2bfloat16(f);
    return *(ushort_t*)&h;
}

// ---------------- phase 0 (1760 blocks): patch GEMM full-K (tasks 0..63, epilogue -> t)
//                  + weight transpose/convert (tasks 64..1759)
__global__ __launch_bounds__(256) void wconv_patch_k(
    const float* __restrict__ Win0, const float* __restrict__ Win1,
    const float* __restrict__ Wout0, const float* __restrict__ Wout1,
    ushort_t* __restrict__ wbuf,
    const float* __restrict__ x, const float* __restrict__ PW,
    const float* __restrict__ pb, const float* __restrict__ pos,
    float* __restrict__ t)
{
    __shared__ __align__(16) unsigned char SM[20480];
    const int task = blockIdx.x;
    const int tid = threadIdx.x;
    if (task >= 64){
        // ---- weight convert: 1696 tile tasks ----
        int wt = task - 64;
        float (*sm)[33] = (float(*)[33])SM;
        const float* src; ushort_t* dst; int R, C, ctiles, tile;
        if (wt < 1184){
            int z = wt / 296; tile = wt - z * 296;              // 37*8 tiles per z
            src = (z & 1 ? Win1 : Win0) + (size_t)(z >> 1) * D * DINPROJ;
            dst = wbuf + (size_t)z * 296960;
            R = D; C = DINPROJ; ctiles = 37;
        } else {
            int k = wt - 1184;
            int z = k >> 7; tile = k & 127;                     // 8*16 tiles per z
            src = (z & 1 ? Wout1 : Wout0) + (size_t)(z >> 1) * DIN * D;
            dst = wbuf + 1187840 + (size_t)z * 131072;
            R = DIN; C = D; ctiles = 8;
        }
        int cx = tile % ctiles, ry = tile / ctiles;
        int c0 = cx * 32, r0 = ry * 32;
        int tx = tid & 31, ty = tid >> 5;
        #pragma unroll
        for (int k = 0; k < 4; ++k){
            int r = r0 + ty + 8 * k, c = c0 + tx;
            sm[ty + 8 * k][tx] = (c < C) ? src[(size_t)r * C + c] : 0.f;
        }
        __syncthreads();
        #pragma unroll
        for (int k = 0; k < 4; ++k){
            int dr = c0 + ty + 8 * k, dc = r0 + tx;
            if (dr < C) dst[(size_t)dr * R + dc] = f2b(sm[tx][ty + 8 * k]);
        }
        return;
    }
    // ---- patch GEMM: 64 tasks = xi(4) x b(16), full K=768, epilogue writes t ----
    ushort_t (*As)[64][40] = (ushort_t(*)[64][40])SM;
    ushort_t (*Bs)[64][40] = (ushort_t(*)[64][40])(SM + 10240);
    const int xi = task & 3, b = task >> 2;
    const int n0 = xi * 64;
    const int lrow = tid >> 2, lc8 = (tid & 3) * 8;
    const int tok = snake_tok(lrow), gy = tok >> 3, gx = tok & 7;
    const float* xb = x + (size_t)b * 3 * IMG * IMG;
    const int wave = tid >> 6, lane = tid & 63;
    const int wm = (wave >> 1) * 32, wn = (wave & 1) * 32;
    const int fro = lane & 15, fk = (lane >> 4) * 8;

    f32x4 acc[2][2];
    #pragma unroll
    for (int i = 0; i < 2; ++i)
        #pragma unroll
        for (int j = 0; j < 2; ++j) acc[i][j] = (f32x4){0.f,0.f,0.f,0.f};

    short8 areg, breg;
    auto gload = [&](int kk){
        int k = kk + lc8;
        int c = k >> 8, rem = k & 255, py = rem >> 4, px = rem & 15;
        const float* srcA = xb + ((size_t)c * IMG + gy * PATCH + py) * IMG + gx * PATCH + px;
        float4 a0 = *(const float4*)(srcA);
        float4 a1 = *(const float4*)(srcA + 4);
        ushort_t ta[8] = {f2b(a0.x),f2b(a0.y),f2b(a0.z),f2b(a0.w),
                          f2b(a1.x),f2b(a1.y),f2b(a1.z),f2b(a1.w)};
        areg = *(short8*)ta;
        const float* srcB = PW + (size_t)(n0 + lrow) * 768 + kk + lc8;
        float4 b0 = *(const float4*)(srcB);
        float4 b1 = *(const float4*)(srcB + 4);
        ushort_t tb[8] = {f2b(b0.x),f2b(b0.y),f2b(b0.z),f2b(b0.w),
                          f2b(b1.x),f2b(b1.y),f2b(b1.z),f2b(b1.w)};
        breg = *(short8*)tb;
    };
    auto sstore = [&](int buf){
        *(short8*)&As[buf][lrow][lc8] = areg;
        *(short8*)&Bs[buf][lrow][lc8] = breg;
    };

    const int nk = 24;
    gload(0); sstore(0);
    __syncthreads();
    for (int kt = 0; kt < nk; ++kt){
        const int buf = kt & 1;
        if (kt + 1 < nk) gload((kt + 1) * 32);
        short8 af[2], bfr[2];
        af[0]  = *(const short8*)&As[buf][wm + fro][fk];
        af[1]  = *(const short8*)&As[buf][wm + 16 + fro][fk];
        bfr[0] = *(const short8*)&Bs[buf][wn + fro][fk];
        bfr[1] = *(const short8*)&Bs[buf][wn + 16 + fro][fk];
        #pragma unroll
        for (int i = 0; i < 2; ++i)
            #pragma unroll
            for (int j = 0; j < 2; ++j)
                acc[i][j] = __builtin_amdgcn_mfma_f32_16x16x32_bf16(af[i], bfr[j], acc[i][j], 0, 0, 0);
        if (kt + 1 < nk) sstore(buf ^ 1);
        __syncthreads();
    }
    #pragma unroll
    for (int i = 0; i < 2; ++i){
        #pragma unroll
        for (int j = 0; j < 2; ++j){
            int col = n0 + wn + j * 16 + (lane & 15);
            #pragma unroll
            for (int r = 0; r < 4; ++r){
                int srow = wm + i * 16 + (lane >> 4) * 4 + r;
                t[(size_t)(b * 64 + srow) * D + col] =
                    acc[i][j][r] + pb[col] + pos[snake_tok(srow) * D + col];
            }
        }
    }
}

// ---------------- in-proj GEMM + rmsnorm prologue + conv/dt epilogue. grid (19,16,2)
// LDS: As(33792) + Bs(10240) = 44032; Ctile aliases As (dead after K loop).
__global__ __launch_bounds__(256) void gemm_in_k(
    const float* __restrict__ T, const float* __restrict__ nw,
    const ushort_t* __restrict__ B0, const ushort_t* __restrict__ B1,
    const float* __restrict__ cw0, const float* __restrict__ cw1,
    const float* __restrict__ cb0, const float* __restrict__ cb1,
    const float* __restrict__ dtb0, const float* __restrict__ dtb1,
    const float* __restrict__ Al0, const float* __restrict__ Al1,
    float* __restrict__ zb0, float* __restrict__ zb1,
    float* __restrict__ xy0, float* __restrict__ xy1,
    float* __restrict__ bc0, float* __restrict__ bc1,
    float* __restrict__ dts0, float* __restrict__ dts1,
    float* __restrict__ cums0, float* __restrict__ cums1)
{
    __shared__ __align__(16) unsigned char SMbuf[44032];
    ushort_t (*As)[264]    = (ushort_t(*)[264])SMbuf;            // 33792
    ushort_t (*Bs)[64][40] = (ushort_t(*)[64][40])(SMbuf + 33792); // 10240
    float (*Ctile)[68]     = (float(*)[68])SMbuf;                // 17408, aliases As
    const int dir = blockIdx.z;
    const ushort_t* __restrict__ Bw = dir ? B1 : B0;
    const int tid = threadIdx.x;
    const int m0 = blockIdx.y * 64, n0 = blockIdx.x * 64;
    const int b = blockIdx.y;
    const int arow = tid >> 2;
    const int wave = tid >> 6, lane = tid & 63;
    const int wm = (wave >> 1) * 32, wn = (wave & 1) * 32;
    const int fro = lane & 15, fk = (lane >> 4) * 8;

    {   // rmsnorm prologue -> As bf16
        const float* src = T + (size_t)(m0 + arow) * D;
        float ss = 0.f;
        #pragma unroll
        for (int i = 0; i < 16; ++i){
            int c = (tid & 3) * 4 + i * 16;
            float4 v = *(const float4*)(src + c);
            ss += v.x*v.x + v.y*v.y + v.z*v.z + v.w*v.w;
        }
        ss += __shfl_xor(ss, 1);
        ss += __shfl_xor(ss, 2);
        float sc = rsqrtf(ss * (1.f / (float)D) + EPS);
        #pragma unroll
        for (int i = 0; i < 16; ++i){
            int c = (tid & 3) * 4 + i * 16;
            float4 v = *(const float4*)(src + c);
            float4 w = *(const float4*)(nw + c);
            us4 o = {f2b(v.x*sc*w.x), f2b(v.y*sc*w.y), f2b(v.z*sc*w.z), f2b(v.w*sc*w.w)};
            *(us4*)&As[arow][c] = o;
        }
    }
    const int lrow = tid >> 2, lc8 = (tid & 3) * 8;
    float4 breg;
    auto gloadB = [&](int kk){
        int gn = n0 + lrow;
        if (gn < DINPROJ) breg = *(const float4*)(Bw + (size_t)gn * D + kk + lc8);
        else breg = make_float4(0.f,0.f,0.f,0.f);
    };
    auto sstoreB = [&](int buf){ *(float4*)&Bs[buf][lrow][lc8] = breg; };

    f32x4 acc[2][2];
    #pragma unroll
    for (int i = 0; i < 2; ++i)
        #pragma unroll
        for (int j = 0; j < 2; ++j) acc[i][j] = (f32x4){0.f,0.f,0.f,0.f};

    gloadB(0); sstoreB(0);
    __syncthreads();
    const int nk = D / 32;
    for (int kt = 0; kt < nk; ++kt){
        const int buf = kt & 1;
        if (kt + 1 < nk) gloadB((kt + 1) * 32);
        short8 af[2], bfr[2];
        af[0]  = *(const short8*)&As[wm + fro][kt * 32 + fk];
        af[1]  = *(const short8*)&As[wm + 16 + fro][kt * 32 + fk];
        bfr[0] = *(const short8*)&Bs[buf][wn + fro][fk];
        bfr[1] = *(const short8*)&Bs[buf][wn + 16 + fro][fk];
        #pragma unroll
        for (int i = 0; i < 2; ++i)
            #pragma unroll
            for (int j = 0; j < 2; ++j)
                acc[i][j] = __builtin_amdgcn_mfma_f32_16x16x32_bf16(af[i], bfr[j], acc[i][j], 0, 0, 0);
        if (kt + 1 < nk) sstoreB(buf ^ 1);
        __syncthreads();
    }
    // K loop ends with __syncthreads -> As dead; Ctile (alias) safe to write.

    if (n0 < DIN){
        float* zb = dir ? zb1 : zb0;
        #pragma unroll
        for (int i = 0; i < 2; ++i){
            #pragma unroll
            for (int j = 0; j < 2; ++j){
                int col = n0 + wn + j * 16 + (lane & 15);
                #pragma unroll
                for (int r = 0; r < 4; ++r){
                    int row = m0 + wm + i * 16 + (lane >> 4) * 4 + r;
                    zb[(size_t)row * DIN + col] = acc[i][j][r];
                }
            }
        }
        return;
    }

    #pragma unroll
    for (int i = 0; i < 2; ++i){
        #pragma unroll
        for (int j = 0; j < 2; ++j){
            int lcol = wn + j * 16 + (lane & 15);
            #pragma unroll
            for (int r = 0; r < 4; ++r){
                int lr = wm + i * 16 + (lane >> 4) * 4 + r;
                Ctile[lr][lcol] = acc[i][j][r];
            }
        }
    }
    __syncthreads();

    if (blockIdx.x < 18){
        const float* cw = dir ? cw1 : cw0;
        const float* cb = dir ? cb1 : cb0;
        float* xy = dir ? xy1 : xy0;
        float* bc = dir ? bc1 : bc0;
        const int c = tid & 63;
        const int cc = n0 - DIN + c;
        const float w0 = cw[cc * DCONV + 0], w1 = cw[cc * DCONV + 1];
        const float w2 = cw[cc * DCONV + 2], w3 = cw[cc * DCONV + 3];
        const float bb = cb[cc];
        #pragma unroll
        for (int rep = 0; rep < 16; ++rep){
            int s = (tid >> 6) + rep * 4;
            float a = bb;
            {
                int sp = s - 3;
                if (sp >= 0) a += w0 * Ctile[dir ? 63 - sp : sp][c];
                sp = s - 2;
                if (sp >= 0) a += w1 * Ctile[dir ? 63 - sp : sp][c];
                sp = s - 1;
                if (sp >= 0) a += w2 * Ctile[dir ? 63 - sp : sp][c];
                a += w3 * Ctile[dir ? 63 - s : s][c];
            }
            float v = silu_f(a);
            if (cc < DIN) xy[(size_t)(b * 64 + s) * DIN + cc] = v;
            else          bc[(size_t)(b * 64 + s) * 128 + (cc - DIN)] = v;
        }
        return;
    }

    {   // dt block
        const float* dtb = dir ? dtb1 : dtb0;
        const float* Al  = dir ? Al1  : Al0;
        float* dts  = dir ? dts1  : dts0;
        float* cums = dir ? cums1 : cums0;
        int s = tid & 63;
        int l = dir ? (63 - s) : s;
        #pragma unroll
        for (int rep = 0; rep < 2; ++rep){
            int h = (tid >> 6) + rep * 4;
            float raw = Ctile[l][h] + dtb[h];
            float dt = softplus_f(raw);
            float val = -expf(Al[h]) * dt;
            #pragma unroll
            for (int o = 1; o < 64; o <<= 1){
                float u = __shfl_up(val, o);
                if (s >= o) val += u;
            }
            dts[(size_t)(b * 64 + s) * H + h]  = dt;
            cums[(size_t)(b * 64 + s) * H + h] = val;
        }
    }
}

// ---------------- S + mask + PV + gate + ssq, s-half split; grid (H, B, 4), 512 thr
__global__ __launch_bounds__(512) void yscan3_k(
    const float* __restrict__ bc0, const float* __restrict__ bc1,
    const float* __restrict__ dts0, const float* __restrict__ dts1,
    const float* __restrict__ cums0, const float* __restrict__ cums1,
    const float* __restrict__ Dp0, const float* __restrict__ Dp1,
    const float* __restrict__ zb0, const float* __restrict__ zb1,
    const float* __restrict__ xy0, const float* __restrict__ xy1,
    float* __restrict__ gb0, float* __restrict__ gb1,
    float* __restrict__ ssq0, float* __restrict__ ssq1)
{
    __shared__ float Bc[64][65];
    __shared__ float Xs[64][65];
    __shared__ float Cc[32][65];
    __shared__ float Am[32][65];
    __shared__ float cumS[64], dtS[64];
    __shared__ float ssqp[16][32];
    const int h = blockIdx.x, b = blockIdx.y;
    const int zz = blockIdx.z;
    const int dir = zz >> 1, half = zz & 1;
    const int s0 = half * 32;
    const float* bc   = dir ? bc1   : bc0;
    const float* dts  = dir ? dts1  : dts0;
    const float* cums = dir ? cums1 : cums0;
    const float* Dp   = dir ? Dp1   : Dp0;
    const float* zb   = dir ? zb1   : zb0;
    const float* xy   = dir ? xy1   : xy0;
    float* gb  = dir ? gb1  : gb0;
    float* ssq = dir ? ssq1 : ssq0;
    const int t = threadIdx.x;

    if (t < 64){
        cumS[t] = cums[(size_t)(b * L + t) * H + h];
        dtS[t]  = dts[(size_t)(b * L + t) * H + h];
    }
    for (int i = t; i < 4096; i += 512){
        int s = i >> 6, n = i & 63;
        Bc[s][n] = bc[(size_t)(b * L + s) * 128 + n];
        Xs[s][n] = xy[(size_t)(b * L + s) * DIN + h * DH + n];
    }
    for (int i = t; i < 2048; i += 512){
        int sl = i >> 6, n = i & 63;
        Cc[sl][n] = bc[(size_t)(b * L + s0 + sl) * 128 + 64 + n];
    }
    __syncthreads();
    for (int i = t; i < 2048; i += 512){
        int sl = i >> 6, j = i & 63;
        int s = s0 + sl;
        float v = 0.f;
        if (j <= s){
            float acc = 0.f;
            #pragma unroll
            for (int n = 0; n < 64; ++n) acc += Cc[sl][n] * Bc[j][n];
            v = acc * expf(cumS[s] - cumS[j]) * dtS[j];
        }
        Am[sl][j] = v;
    }
    __syncthreads();
    {
        const int sl = t & 31, pg = t >> 5;
        const int s = s0 + sl;
        const int l = dir ? (63 - s) : s;
        const size_t row = (size_t)(b * 64 + l);
        const float dp = Dp[h];
        float acc[4];
        #pragma unroll
        for (int pp = 0; pp < 4; ++pp) acc[pp] = dp * Xs[s][pg * 4 + pp];
        #pragma unroll
        for (int j = 0; j < 64; ++j){
            float am = Am[sl][j];
            #pragma unroll
            for (int pp = 0; pp < 4; ++pp)
                acc[pp] = fmaf(am, Xs[j][pg * 4 + pp], acc[pp]);
        }
        float4 z4 = *(const float4*)(zb + row * DIN + h * DH + pg * 4);
        float zv[4] = {z4.x, z4.y, z4.z, z4.w};
        float g2 = 0.f;
        float gout[4];
        #pragma unroll
        for (int pp = 0; pp < 4; ++pp){
            float g = acc[pp] * silu_f(zv[pp]);
            gout[pp] = g;
            g2 += g * g;
        }
        ssqp[pg][sl] = g2;
        *(float4*)(gb + row * DIN + h * DH + pg * 4) =
            make_float4(gout[0], gout[1], gout[2], gout[3]);
    }
    __syncthreads();
    if (t < 32){
        int s = s0 + t;
        int ll = dir ? (63 - s) : s;
        float v = 0.f;
        #pragma unroll
        for (int q = 0; q < 16; ++q) v += ssqp[q][t];
        ssq[(size_t)(b * 64 + ll) * H + h] = v;
    }
}

// ---------------- out-proj GEMM split-K=8 + gate-norm prologue; grid (4,16,8)
__global__ __launch_bounds__(256) void gemm_out_k(
    const float* __restrict__ G0, const float* __restrict__ G1,
    const float* __restrict__ ssq0, const float* __restrict__ ssq1,
    const float* __restrict__ gn0, const float* __restrict__ gn1,
    const ushort_t* __restrict__ B0, const ushort_t* __restrict__ B1,
    float* __restrict__ part)
{
    __shared__ __align__(16) ushort_t As[2][64][40];
    __shared__ __align__(16) ushort_t Bs[2][64][40];
    __shared__ float scl[64];
    const int tid = threadIdx.x;
    const int n0 = blockIdx.x * 64, m0 = blockIdx.y * 64;
    const int z = blockIdx.z;
    const int dir = z >> 2;
    const int kbase = (z & 3) * 128;
    const float* __restrict__ G   = dir ? G1   : G0;
    const float* __restrict__ ssq = dir ? ssq1 : ssq0;
    const float* __restrict__ gnw = dir ? gn1  : gn0;
    const ushort_t* __restrict__ B = dir ? B1 : B0;
    const int lrow = tid >> 2, lc8 = (tid & 3) * 8;
    const int wave = tid >> 6, lane = tid & 63;
    const int wm = (wave >> 1) * 32, wn = (wave & 1) * 32;
    const int fro = lane & 15, fk = (lane >> 4) * 8;

    if (tid < 64){
        const float* sr = ssq + (size_t)(m0 + tid) * H;
        float v = (sr[0] + sr[1]) + (sr[2] + sr[3]) + (sr[4] + sr[5]) + (sr[6] + sr[7]);
        scl[tid] = rsqrtf(v * (1.f / (float)DIN) + EPS);
    }
    __syncthreads();

    short8 areg; float4 breg;
    auto gload = [&](int kk){
        const float* src = G + (size_t)(m0 + lrow) * DIN + kk + lc8;
        float4 a0 = *(const float4*)(src);
        float4 a1 = *(const float4*)(src + 4);
        const float* gw = gnw + kk + lc8;
        float4 w0 = *(const float4*)(gw);
        float4 w1 = *(const float4*)(gw + 4);
        float sc = scl[lrow];
        ushort_t ta[8] = {f2b(a0.x*sc*w0.x), f2b(a0.y*sc*w0.y), f2b(a0.z*sc*w0.z), f2b(a0.w*sc*w0.w),
                          f2b(a1.x*sc*w1.x), f2b(a1.y*sc*w1.y), f2b(a1.z*sc*w1.z), f2b(a1.w*sc*w1.w)};
        areg = *(short8*)ta;
        breg = *(const float4*)(B + (size_t)(n0 + lrow) * DIN + kk + lc8);
    };
    auto sstore = [&](int buf){
        *(short8*)&As[buf][lrow][lc8] = areg;
        *(float4*)&Bs[buf][lrow][lc8] = breg;
    };

    f32x4 acc[2][2];
    #pragma unroll
    for (int i = 0; i < 2; ++i)
        #pragma unroll
        for (int j = 0; j < 2; ++j) acc[i][j] = (f32x4){0.f,0.f,0.f,0.f};

    const int nk = 4;
    gload(kbase); sstore(0);
    __syncthreads();
    for (int kt = 0; kt < nk; ++kt){
        const int buf = kt & 1;
        if (kt + 1 < nk) gload(kbase + (kt + 1) * 32);
        short8 af[2], bfr[2];
        af[0]  = *(const short8*)&As[buf][wm + fro][fk];
        af[1]  = *(const short8*)&As[buf][wm + 16 + fro][fk];
        bfr[0] = *(const short8*)&Bs[buf][wn + fro][fk];
        bfr[1] = *(const short8*)&Bs[buf][wn + 16 + fro][fk];
        #pragma unroll
        for (int i = 0; i < 2; ++i)
            #pragma unroll
            for (int j = 0; j < 2; ++j)
                acc[i][j] = __builtin_amdgcn_mfma_f32_16x16x32_bf16(af[i], bfr[j], acc[i][j], 0, 0, 0);
        if (kt + 1 < nk) sstore(buf ^ 1);
        __syncthreads();
    }
    float* Cp = part + (size_t)z * SLAB;
    #pragma unroll
    for (int i = 0; i < 2; ++i){
        #pragma unroll
        for (int j = 0; j < 2; ++j){
            int col = n0 + wn + j * 16 + (lane & 15);
            #pragma unroll
            for (int r = 0; r < 4; ++r){
                int row = m0 + wm + i * 16 + (lane >> 4) * 4 + r;
                Cp[(size_t)row * D + col] = acc[i][j][r];
            }
        }
    }
}

// ---------------- out reduce (layer 0 only): t += 0.5 * sum(8 partials)
__global__ void out_red_k(const float* __restrict__ part, float* __restrict__ t){
    int i = blockIdx.x * 256 + threadIdx.x;
    float v = 0.f;
    #pragma unroll
    for (int r = 0; r < 8; ++r) v += part[i + r * SLAB];
    t[i] += 0.5f * v;
}

// ---------------- final: teff = t + 0.5*sum(part), rmsnorm rows, partial mean
__global__ void finalmean_k(const float* __restrict__ T, const float* __restrict__ part,
                            const float* __restrict__ fw, float* __restrict__ tm8){
    __shared__ float sm4[4];
    int b = blockIdx.x, q = blockIdx.y;
    int d = threadIdx.x;
    float a = 0.f;
    for (int r = 0; r < 8; ++r){
        int row = b * 64 + q * 8 + r;
        size_t o = (size_t)row * D + d;
        float pv = 0.f;
        #pragma unroll
        for (int u = 0; u < 8; ++u) pv += part[o + (size_t)u * SLAB];
        float v = T[o] + 0.5f * pv;
        float ssl = v * v;
        #pragma unroll
        for (int off = 32; off > 0; off >>= 1) ssl += __shfl_down(ssl, off);
        if ((threadIdx.x & 63) == 0) sm4[threadIdx.x >> 6] = ssl;
        __syncthreads();
        float ss = sm4[0] + sm4[1] + sm4[2] + sm4[3];
        __syncthreads();
        float sc = rsqrtf(ss / (float)D + EPS);
        a += v * sc;
    }
    tm8[(q * BATCH + b) * D + d] = a * (1.f / (float)L) * fw[d];
}

// ---------------- head: single kernel, K=256, tm8 slabs summed in LDS, +bias
__global__ void head_k(const float* __restrict__ tm8, const float* __restrict__ hw,
                       const float* __restrict__ hb, float* __restrict__ out){
    __shared__ float trs[2][256];
    int i0 = blockIdx.x * 256;
    int mmin = i0 / NCLS;
    int t = threadIdx.x;
    #pragma unroll
    for (int mm = 0; mm < 2; ++mm){
        int m = mmin + mm;
        float v = 0.f;
        if (m < BATCH){
            #pragma unroll
            for (int q = 0; q < 8; ++q)
                v += tm8[(q * BATCH + m) * D + t];
        }
        trs[mm][t] = v;
    }
    __syncthreads();
    int i = i0 + t;
    if (i >= BATCH * NCLS) return;
    int m = i / NCLS, n = i - m * NCLS;
    const float* tr = trs[m - mmin];
    const float* hc = hw + n;
    float a0 = 0.f, a1 = 0.f, a2 = 0.f, a3 = 0.f;
    #pragma unroll 4
    for (int k = 0; k < D; k += 4){
        a0 = fmaf(tr[k],     hc[(size_t)k * NCLS],       a0);
        a1 = fmaf(tr[k + 1], hc[(size_t)(k + 1) * NCLS], a1);
        a2 = fmaf(tr[k + 2], hc[(size_t)(k + 2) * NCLS], a2);
        a3 = fmaf(tr[k + 3], hc[(size_t)(k + 3) * NCLS], a3);
    }
    out[i] = (a0 + a1) + (a2 + a3) + hb[n];
}

extern "C" void kernel_launch(void* const* d_in, const int* in_sizes, int n_in,
                              void* d_out, int out_size, void* d_ws, size_t ws_size,
                              hipStream_t stream){
    (void)in_sizes; (void)n_in; (void)out_size; (void)ws_size;
    const float* x       = (const float*)d_in[0];
    const float* patch_w = (const float*)d_in[1];
    const float* patch_b = (const float*)d_in[2];
    const float* pos     = (const float*)d_in[3];
    const float* norms_w = (const float*)d_in[4];
    const float* final_w = (const float*)d_in[5];
    const float* head_w  = (const float*)d_in[6];
    const float* head_b  = (const float*)d_in[7];
    const float* Win[2]  = {(const float*)d_in[8],  (const float*)d_in[16]};
    const float* cw[2]   = {(const float*)d_in[9],  (const float*)d_in[17]};
    const float* cb[2]   = {(const float*)d_in[10], (const float*)d_in[18]};
    const float* dtb[2]  = {(const float*)d_in[11], (const float*)d_in[19]};
    const float* Alog[2] = {(const float*)d_in[12], (const float*)d_in[20]};
    const float* Dp[2]   = {(const float*)d_in[13], (const float*)d_in[21]};
    const float* gn[2]   = {(const float*)d_in[14], (const float*)d_in[22]};
    const float* Wout[2] = {(const float*)d_in[15], (const float*)d_in[23]};

    float* ws = (float*)d_ws;
    float* t     = ws;                   // 262144
    float* tm8   = t     + 262144;       // 32768
    float* zb0   = tm8   + 32768;        // 524288
    float* zb1   = zb0   + 524288;
    float* xy0   = zb1   + 524288;       // 524288 (xs)
    float* xy1   = xy0   + 524288;
    float* gb0   = xy1   + 524288;       // 524288 (gate output)
    float* gb1   = gb0   + 524288;
    float* bc0   = gb1   + 524288;       // 131072
    float* bc1   = bc0   + 131072;
    float* dts0  = bc1   + 131072;       // 8192 x6
    float* dts1  = dts0  + 8192;
    float* cum0  = dts1  + 8192;
    float* cum1  = cum0  + 8192;
    float* ssq0  = cum1  + 8192;
    float* ssq1  = ssq0  + 8192;
    float* partO = ssq1  + 8192;         // 2097152
    float* f32end = partO + 2097152;

    ushort_t* wbuf = (ushort_t*)f32end;          // 1712128
    ushort_t* win_bf  = wbuf;                    // 4 x 296960
    ushort_t* wout_bf = wbuf + 1187840;          // 4 x 131072

    const int BL = BATCH * L;   // 1024

    wconv_patch_k<<<1760, 256, 0, stream>>>(
        Win[0], Win[1], Wout[0], Wout[1], wbuf, x, patch_w, patch_b, pos, t);

    for (int i = 0; i < DEPTH; ++i){
        const float* cw0  = cw[0]   + (size_t)i * CDIM * DCONV;
        const float* cw1  = cw[1]   + (size_t)i * CDIM * DCONV;
        const float* cb0  = cb[0]   + (size_t)i * CDIM;
        const float* cb1  = cb[1]   + (size_t)i * CDIM;
        const float* dtb0 = dtb[0]  + (size_t)i * H;
        const float* dtb1 = dtb[1]  + (size_t)i * H;
        const float* Al0  = Alog[0] + (size_t)i * H;
        const float* Al1  = Alog[1] + (size_t)i * H;
        const float* Dp0  = Dp[0]   + (size_t)i * H;
        const float* Dp1  = Dp[1]   + (size_t)i * H;
        const float* gn0  = gn[0]   + (size_t)i * DIN;
        const float* gn1  = gn[1]   + (size_t)i * DIN;
        const ushort_t* Wi0 = win_bf  + (size_t)(2 * i + 0) * 296960;
        const ushort_t* Wi1 = win_bf  + (size_t)(2 * i + 1) * 296960;
        const ushort_t* Wo0 = wout_bf + (size_t)(2 * i + 0) * 131072;
        const ushort_t* Wo1 = wout_bf + (size_t)(2 * i + 1) * 131072;

        gemm_in_k<<<dim3(19, 16, 2), 256, 0, stream>>>(
            t, norms_w + i * D, Wi0, Wi1, cw0, cw1, cb0, cb1, dtb0, dtb1,
            Al0, Al1, zb0, zb1, xy0, xy1, bc0, bc1, dts0, dts1, cum0, cum1);
        yscan3_k<<<dim3(H, BATCH, 4), 512, 0, stream>>>(
            bc0, bc1, dts0, dts1, cum0, cum1, Dp0, Dp1, zb0, zb1,
            xy0, xy1, gb0, gb1, ssq0, ssq1);
        gemm_out_k<<<dim3(4, 16, 8), 256, 0, stream>>>(
            gb0, gb1, ssq0, ssq1, gn0, gn1, Wo0, Wo1, partO);
        if (i == 0)
            out_red_k<<<BL, 256, 0, stream>>>(partO, t);
    }

    finalmean_k<<<dim3(BATCH, 8), 256, 0, stream>>>(t, partO, final_w, tm8);
    head_k<<<(BATCH * NCLS + 255) / 256, 256, 0, stream>>>(
        tm8, head_w, head_b, (float*)d_out);
}

// Round 16
// 125.684 us; speedup vs baseline: 1.1030x; 1.1030x over previous
//
#include <hip/hip_runtime.h>
#include <hip/hip_bf16.h>
#include <math.h>

#define IMG 128
#define PATCH 16
#define L 64
#define D 256
#define DIN 512
#define DH 64
#define H 8
#define NSTATE 64
#define DCONV 4
#define DEPTH 2
#define NCLS 1000
#define BATCH 16
#define DINPROJ 1160   // 2*DIN + 2*N + H
#define CDIM 640       // DIN + 2*N
#define EPS 1e-6f
#define SLAB (BATCH * L * D)   // 262144

typedef __attribute__((ext_vector_type(8))) short short8;
typedef __attribute__((ext_vector_type(4))) float f32x4;
typedef __attribute__((ext_vector_type(4))) unsigned short us4;
typedef unsigned short ushort_t;

__device__ __forceinline__ int snake_tok(int s){
    int r = s >> 3, c = s & 7;
    return (r & 1) ? (r * 8 + (7 - c)) : (r * 8 + c);
}
__device__ __forceinline__ float silu_f(float x){ return x / (1.f + expf(-x)); }
__device__ __forceinline__ float softplus_f(float x){ return x > 20.f ? x : log1pf(expf(x)); }
__device__ __forceinline__ ushort_t f2b(float f){
    __hip_bfloat16 h = __float2bfloat16(f);
    return *(ushort_t*)&h;
}

// ---------------- phase 0 (flattened, 2208 blocks): wconv (0..1695) + patch GEMM sK=8 (1696..2207)
__global__ __launch_bounds__(256) void wconv_patch_k(
    const float* __restrict__ Win0, const float* __restrict__ Win1,
    const float* __restrict__ Wout0, const float* __restrict__ Wout1,
    ushort_t* __restrict__ wbuf,
    const float* __restrict__ x, const float* __restrict__ PW,
    float* __restrict__ partP)
{
    __shared__ __align__(16) unsigned char SM[20480];
    const int task = blockIdx.x;
    const int tid = threadIdx.x;
    if (task < 1696){
        float (*sm)[33] = (float(*)[33])SM;
        const float* src; ushort_t* dst; int R, C, ctiles, tile;
        if (task < 1184){
            int z = task / 296; tile = task - z * 296;          // 37*8 tiles per z
            src = (z & 1 ? Win1 : Win0) + (size_t)(z >> 1) * D * DINPROJ;
            dst = wbuf + (size_t)z * 296960;
            R = D; C = DINPROJ; ctiles = 37;
        } else {
            int k = task - 1184;
            int z = k >> 7; tile = k & 127;                     // 8*16 tiles per z
            src = (z & 1 ? Wout1 : Wout0) + (size_t)(z >> 1) * DIN * D;
            dst = wbuf + 1187840 + (size_t)z * 131072;
            R = DIN; C = D; ctiles = 8;
        }
        int cx = tile % ctiles, ry = tile / ctiles;
        int c0 = cx * 32, r0 = ry * 32;
        int tx = tid & 31, ty = tid >> 5;
        #pragma unroll
        for (int k = 0; k < 4; ++k){
            int r = r0 + ty + 8 * k, c = c0 + tx;
            sm[ty + 8 * k][tx] = (c < C) ? src[(size_t)r * C + c] : 0.f;
        }
        __syncthreads();
        #pragma unroll
        for (int k = 0; k < 4; ++k){
            int dr = c0 + ty + 8 * k, dc = r0 + tx;
            if (dr < C) dst[(size_t)dr * R + dc] = f2b(sm[tx][ty + 8 * k]);
        }
        return;
    }
    // ---- patch GEMM: 512 tasks = xi(4) x b(16) x split(8), K=96 each ----
    ushort_t (*As)[64][40] = (ushort_t(*)[64][40])SM;
    ushort_t (*Bs)[64][40] = (ushort_t(*)[64][40])(SM + 10240);
    const int pt = task - 1696;
    const int xi = pt & 3, b = (pt >> 2) & 15, split = pt >> 6;
    const int n0 = xi * 64;
    const int kbase = split * 96;
    const int lrow = tid >> 2, lc8 = (tid & 3) * 8;
    const int tok = snake_tok(lrow), gy = tok >> 3, gx = tok & 7;
    const float* xb = x + (size_t)b * 3 * IMG * IMG;
    const int wave = tid >> 6, lane = tid & 63;
    const int wm = (wave >> 1) * 32, wn = (wave & 1) * 32;
    const int fro = lane & 15, fk = (lane >> 4) * 8;

    f32x4 acc[2][2];
    #pragma unroll
    for (int i = 0; i < 2; ++i)
        #pragma unroll
        for (int j = 0; j < 2; ++j) acc[i][j] = (f32x4){0.f,0.f,0.f,0.f};

    short8 areg, breg;
    auto gload = [&](int kk){
        int k = kk + lc8;
        int c = k >> 8, rem = k & 255, py = rem >> 4, px = rem & 15;
        const float* srcA = xb + ((size_t)c * IMG + gy * PATCH + py) * IMG + gx * PATCH + px;
        float4 a0 = *(const float4*)(srcA);
        float4 a1 = *(const float4*)(srcA + 4);
        ushort_t ta[8] = {f2b(a0.x),f2b(a0.y),f2b(a0.z),f2b(a0.w),
                          f2b(a1.x),f2b(a1.y),f2b(a1.z),f2b(a1.w)};
        areg = *(short8*)ta;
        const float* srcB = PW + (size_t)(n0 + lrow) * 768 + kk + lc8;
        float4 b0 = *(const float4*)(srcB);
        float4 b1 = *(const float4*)(srcB + 4);
        ushort_t tb[8] = {f2b(b0.x),f2b(b0.y),f2b(b0.z),f2b(b0.w),
                          f2b(b1.x),f2b(b1.y),f2b(b1.z),f2b(b1.w)};
        breg = *(short8*)tb;
    };
    auto sstore = [&](int buf){
        *(short8*)&As[buf][lrow][lc8] = areg;
        *(short8*)&Bs[buf][lrow][lc8] = breg;
    };

    const int nk = 3;
    gload(kbase); sstore(0);
    __syncthreads();
    for (int kt = 0; kt < nk; ++kt){
        const int buf = kt & 1;
        if (kt + 1 < nk) gload(kbase + (kt + 1) * 32);
        short8 af[2], bfr[2];
        af[0]  = *(const short8*)&As[buf][wm + fro][fk];
        af[1]  = *(const short8*)&As[buf][wm + 16 + fro][fk];
        bfr[0] = *(const short8*)&Bs[buf][wn + fro][fk];
        bfr[1] = *(const short8*)&Bs[buf][wn + 16 + fro][fk];
        #pragma unroll
        for (int i = 0; i < 2; ++i)
            #pragma unroll
            for (int j = 0; j < 2; ++j)
                acc[i][j] = __builtin_amdgcn_mfma_f32_16x16x32_bf16(af[i], bfr[j], acc[i][j], 0, 0, 0);
        if (kt + 1 < nk) sstore(buf ^ 1);
        __syncthreads();
    }
    float* Cp = partP + (size_t)split * SLAB;
    #pragma unroll
    for (int i = 0; i < 2; ++i){
        #pragma unroll
        for (int j = 0; j < 2; ++j){
            int col = n0 + wn + j * 16 + (lane & 15);
            #pragma unroll
            for (int r = 0; r < 4; ++r){
                int srow = wm + i * 16 + (lane >> 4) * 4 + r;
                Cp[(size_t)(b * 64 + srow) * D + col] = acc[i][j][r];
            }
        }
    }
}

// ---------------- patch reduce: t = sum(8 partials) + pb + pos
__global__ void patch_red_k(const float* __restrict__ part, const float* __restrict__ pb,
                            const float* __restrict__ pos, float* __restrict__ t){
    int i = blockIdx.x * 256 + threadIdx.x;
    int d = i & (D - 1), s = (i >> 8) & (L - 1);
    float v = 0.f;
    #pragma unroll
    for (int r = 0; r < 8; ++r) v += part[i + r * SLAB];
    t[i] = v + pb[d] + pos[snake_tok(s) * D + d];
}

// ---------------- in-proj GEMM + rmsnorm prologue + conv/dt epilogue. grid (19,16,2)
// LDS: As(33792) + Bs(10240) = 44032; Ctile aliases As (dead after K loop) -> 3 blocks/CU.
__global__ __launch_bounds__(256) void gemm_in_k(
    const float* __restrict__ T, const float* __restrict__ nw,
    const ushort_t* __restrict__ B0, const ushort_t* __restrict__ B1,
    const float* __restrict__ cw0, const float* __restrict__ cw1,
    const float* __restrict__ cb0, const float* __restrict__ cb1,
    const float* __restrict__ dtb0, const float* __restrict__ dtb1,
    const float* __restrict__ Al0, const float* __restrict__ Al1,
    float* __restrict__ zb0, float* __restrict__ zb1,
    float* __restrict__ xy0, float* __restrict__ xy1,
    float* __restrict__ bc0, float* __restrict__ bc1,
    float* __restrict__ dts0, float* __restrict__ dts1,
    float* __restrict__ cums0, float* __restrict__ cums1)
{
    __shared__ __align__(16) unsigned char SMbuf[44032];
    ushort_t (*As)[264]    = (ushort_t(*)[264])SMbuf;              // 33792
    ushort_t (*Bs)[64][40] = (ushort_t(*)[64][40])(SMbuf + 33792); // 10240
    float (*Ctile)[68]     = (float(*)[68])SMbuf;                  // 17408, aliases As
    const int dir = blockIdx.z;
    const ushort_t* __restrict__ Bw = dir ? B1 : B0;
    const int tid = threadIdx.x;
    const int m0 = blockIdx.y * 64, n0 = blockIdx.x * 64;
    const int b = blockIdx.y;
    const int arow = tid >> 2;
    const int wave = tid >> 6, lane = tid & 63;
    const int wm = (wave >> 1) * 32, wn = (wave & 1) * 32;
    const int fro = lane & 15, fk = (lane >> 4) * 8;

    {   // rmsnorm prologue -> As bf16
        const float* src = T + (size_t)(m0 + arow) * D;
        float ss = 0.f;
        #pragma unroll
        for (int i = 0; i < 16; ++i){
            int c = (tid & 3) * 4 + i * 16;
            float4 v = *(const float4*)(src + c);
            ss += v.x*v.x + v.y*v.y + v.z*v.z + v.w*v.w;
        }
        ss += __shfl_xor(ss, 1);
        ss += __shfl_xor(ss, 2);
        float sc = rsqrtf(ss * (1.f / (float)D) + EPS);
        #pragma unroll
        for (int i = 0; i < 16; ++i){
            int c = (tid & 3) * 4 + i * 16;
            float4 v = *(const float4*)(src + c);
            float4 w = *(const float4*)(nw + c);
            us4 o = {f2b(v.x*sc*w.x), f2b(v.y*sc*w.y), f2b(v.z*sc*w.z), f2b(v.w*sc*w.w)};
            *(us4*)&As[arow][c] = o;
        }
    }
    const int lrow = tid >> 2, lc8 = (tid & 3) * 8;
    float4 breg;
    auto gloadB = [&](int kk){
        int gn = n0 + lrow;
        if (gn < DINPROJ) breg = *(const float4*)(Bw + (size_t)gn * D + kk + lc8);
        else breg = make_float4(0.f,0.f,0.f,0.f);
    };
    auto sstoreB = [&](int buf){ *(float4*)&Bs[buf][lrow][lc8] = breg; };

    f32x4 acc[2][2];
    #pragma unroll
    for (int i = 0; i < 2; ++i)
        #pragma unroll
        for (int j = 0; j < 2; ++j) acc[i][j] = (f32x4){0.f,0.f,0.f,0.f};

    gloadB(0); sstoreB(0);
    __syncthreads();
    const int nk = D / 32;
    for (int kt = 0; kt < nk; ++kt){
        const int buf = kt & 1;
        if (kt + 1 < nk) gloadB((kt + 1) * 32);
        short8 af[2], bfr[2];
        af[0]  = *(const short8*)&As[wm + fro][kt * 32 + fk];
        af[1]  = *(const short8*)&As[wm + 16 + fro][kt * 32 + fk];
        bfr[0] = *(const short8*)&Bs[buf][wn + fro][fk];
        bfr[1] = *(const short8*)&Bs[buf][wn + 16 + fro][fk];
        #pragma unroll
        for (int i = 0; i < 2; ++i)
            #pragma unroll
            for (int j = 0; j < 2; ++j)
                acc[i][j] = __builtin_amdgcn_mfma_f32_16x16x32_bf16(af[i], bfr[j], acc[i][j], 0, 0, 0);
        if (kt + 1 < nk) sstoreB(buf ^ 1);
        __syncthreads();
    }
    // K loop ends with __syncthreads -> As dead; Ctile (alias) safe to write.

    if (n0 < DIN){
        float* zb = dir ? zb1 : zb0;
        #pragma unroll
        for (int i = 0; i < 2; ++i){
            #pragma unroll
            for (int j = 0; j < 2; ++j){
                int col = n0 + wn + j * 16 + (lane & 15);
                #pragma unroll
                for (int r = 0; r < 4; ++r){
                    int row = m0 + wm + i * 16 + (lane >> 4) * 4 + r;
                    zb[(size_t)row * DIN + col] = acc[i][j][r];
                }
            }
        }
        return;
    }

    #pragma unroll
    for (int i = 0; i < 2; ++i){
        #pragma unroll
        for (int j = 0; j < 2; ++j){
            int lcol = wn + j * 16 + (lane & 15);
            #pragma unroll
            for (int r = 0; r < 4; ++r){
                int lr = wm + i * 16 + (lane >> 4) * 4 + r;
                Ctile[lr][lcol] = acc[i][j][r];
            }
        }
    }
    __syncthreads();

    if (blockIdx.x < 18){
        const float* cw = dir ? cw1 : cw0;
        const float* cb = dir ? cb1 : cb0;
        float* xy = dir ? xy1 : xy0;
        float* bc = dir ? bc1 : bc0;
        const int c = tid & 63;
        const int cc = n0 - DIN + c;
        const float w0 = cw[cc * DCONV + 0], w1 = cw[cc * DCONV + 1];
        const float w2 = cw[cc * DCONV + 2], w3 = cw[cc * DCONV + 3];
        const float bb = cb[cc];
        #pragma unroll
        for (int rep = 0; rep < 16; ++rep){
            int s = (tid >> 6) + rep * 4;
            float a = bb;
            {
                int sp = s - 3;
                if (sp >= 0) a += w0 * Ctile[dir ? 63 - sp : sp][c];
                sp = s - 2;
                if (sp >= 0) a += w1 * Ctile[dir ? 63 - sp : sp][c];
                sp = s - 1;
                if (sp >= 0) a += w2 * Ctile[dir ? 63 - sp : sp][c];
                a += w3 * Ctile[dir ? 63 - s : s][c];
            }
            float v = silu_f(a);
            if (cc < DIN) xy[(size_t)(b * 64 + s) * DIN + cc] = v;
            else          bc[(size_t)(b * 64 + s) * 128 + (cc - DIN)] = v;
        }
        return;
    }

    {   // dt block
        const float* dtb = dir ? dtb1 : dtb0;
        const float* Al  = dir ? Al1  : Al0;
        float* dts  = dir ? dts1  : dts0;
        float* cums = dir ? cums1 : cums0;
        int s = tid & 63;
        int l = dir ? (63 - s) : s;
        #pragma unroll
        for (int rep = 0; rep < 2; ++rep){
            int h = (tid >> 6) + rep * 4;
            float raw = Ctile[l][h] + dtb[h];
            float dt = softplus_f(raw);
            float val = -expf(Al[h]) * dt;
            #pragma unroll
            for (int o = 1; o < 64; o <<= 1){
                float u = __shfl_up(val, o);
                if (s >= o) val += u;
            }
            dts[(size_t)(b * 64 + s) * H + h]  = dt;
            cums[(size_t)(b * 64 + s) * H + h] = val;
        }
    }
}

// ---------------- S + mask + PV + gate + ssq, s-half split; grid (H, B, 4), 512 thr
__global__ __launch_bounds__(512) void yscan3_k(
    const float* __restrict__ bc0, const float* __restrict__ bc1,
    const float* __restrict__ dts0, const float* __restrict__ dts1,
    const float* __restrict__ cums0, const float* __restrict__ cums1,
    const float* __restrict__ Dp0, const float* __restrict__ Dp1,
    const float* __restrict__ zb0, const float* __restrict__ zb1,
    const float* __restrict__ xy0, const float* __restrict__ xy1,
    float* __restrict__ gb0, float* __restrict__ gb1,
    float* __restrict__ ssq0, float* __restrict__ ssq1)
{
    __shared__ float Bc[64][65];
    __shared__ float Xs[64][65];
    __shared__ float Cc[32][65];
    __shared__ float Am[32][65];
    __shared__ float cumS[64], dtS[64];
    __shared__ float ssqp[16][32];
    const int h = blockIdx.x, b = blockIdx.y;
    const int zz = blockIdx.z;
    const int dir = zz >> 1, half = zz & 1;
    const int s0 = half * 32;
    const float* bc   = dir ? bc1   : bc0;
    const float* dts  = dir ? dts1  : dts0;
    const float* cums = dir ? cums1 : cums0;
    const float* Dp   = dir ? Dp1   : Dp0;
    const float* zb   = dir ? zb1   : zb0;
    const float* xy   = dir ? xy1   : xy0;
    float* gb  = dir ? gb1  : gb0;
    float* ssq = dir ? ssq1 : ssq0;
    const int t = threadIdx.x;

    if (t < 64){
        cumS[t] = cums[(size_t)(b * L + t) * H + h];
        dtS[t]  = dts[(size_t)(b * L + t) * H + h];
    }
    for (int i = t; i < 4096; i += 512){
        int s = i >> 6, n = i & 63;
        Bc[s][n] = bc[(size_t)(b * L + s) * 128 + n];
        Xs[s][n] = xy[(size_t)(b * L + s) * DIN + h * DH + n];
    }
    for (int i = t; i < 2048; i += 512){
        int sl = i >> 6, n = i & 63;
        Cc[sl][n] = bc[(size_t)(b * L + s0 + sl) * 128 + 64 + n];
    }
    __syncthreads();
    for (int i = t; i < 2048; i += 512){
        int sl = i >> 6, j = i & 63;
        int s = s0 + sl;
        float v = 0.f;
        if (j <= s){
            float acc = 0.f;
            #pragma unroll
            for (int n = 0; n < 64; ++n) acc += Cc[sl][n] * Bc[j][n];
            v = acc * expf(cumS[s] - cumS[j]) * dtS[j];
        }
        Am[sl][j] = v;
    }
    __syncthreads();
    {
        const int sl = t & 31, pg = t >> 5;
        const int s = s0 + sl;
        const int l = dir ? (63 - s) : s;
        const size_t row = (size_t)(b * 64 + l);
        const float dp = Dp[h];
        float acc[4];
        #pragma unroll
        for (int pp = 0; pp < 4; ++pp) acc[pp] = dp * Xs[s][pg * 4 + pp];
        #pragma unroll
        for (int j = 0; j < 64; ++j){
            float am = Am[sl][j];
            #pragma unroll
            for (int pp = 0; pp < 4; ++pp)
                acc[pp] = fmaf(am, Xs[j][pg * 4 + pp], acc[pp]);
        }
        float4 z4 = *(const float4*)(zb + row * DIN + h * DH + pg * 4);
        float zv[4] = {z4.x, z4.y, z4.z, z4.w};
        float g2 = 0.f;
        float gout[4];
        #pragma unroll
        for (int pp = 0; pp < 4; ++pp){
            float g = acc[pp] * silu_f(zv[pp]);
            gout[pp] = g;
            g2 += g * g;
        }
        ssqp[pg][sl] = g2;
        *(float4*)(gb + row * DIN + h * DH + pg * 4) =
            make_float4(gout[0], gout[1], gout[2], gout[3]);
    }
    __syncthreads();
    if (t < 32){
        int s = s0 + t;
        int ll = dir ? (63 - s) : s;
        float v = 0.f;
        #pragma unroll
        for (int q = 0; q < 16; ++q) v += ssqp[q][t];
        ssq[(size_t)(b * 64 + ll) * H + h] = v;
    }
}

// ---------------- out-proj GEMM split-K=8 + gate-norm prologue; grid (4,16,8)
__global__ __launch_bounds__(256) void gemm_out_k(
    const float* __restrict__ G0, const float* __restrict__ G1,
    const float* __restrict__ ssq0, const float* __restrict__ ssq1,
    const float* __restrict__ gn0, const float* __restrict__ gn1,
    const ushort_t* __restrict__ B0, const ushort_t* __restrict__ B1,
    float* __restrict__ part)
{
    __shared__ __align__(16) ushort_t As[2][64][40];
    __shared__ __align__(16) ushort_t Bs[2][64][40];
    __shared__ float scl[64];
    const int tid = threadIdx.x;
    const int n0 = blockIdx.x * 64, m0 = blockIdx.y * 64;
    const int z = blockIdx.z;
    const int dir = z >> 2;
    const int kbase = (z & 3) * 128;
    const float* __restrict__ G   = dir ? G1   : G0;
    const float* __restrict__ ssq = dir ? ssq1 : ssq0;
    const float* __restrict__ gnw = dir ? gn1  : gn0;
    const ushort_t* __restrict__ B = dir ? B1 : B0;
    const int lrow = tid >> 2, lc8 = (tid & 3) * 8;
    const int wave = tid >> 6, lane = tid & 63;
    const int wm = (wave >> 1) * 32, wn = (wave & 1) * 32;
    const int fro = lane & 15, fk = (lane >> 4) * 8;

    if (tid < 64){
        const float* sr = ssq + (size_t)(m0 + tid) * H;
        float v = (sr[0] + sr[1]) + (sr[2] + sr[3]) + (sr[4] + sr[5]) + (sr[6] + sr[7]);
        scl[tid] = rsqrtf(v * (1.f / (float)DIN) + EPS);
    }
    __syncthreads();

    short8 areg; float4 breg;
    auto gload = [&](int kk){
        const float* src = G + (size_t)(m0 + lrow) * DIN + kk + lc8;
        float4 a0 = *(const float4*)(src);
        float4 a1 = *(const float4*)(src + 4);
        const float* gw = gnw + kk + lc8;
        float4 w0 = *(const float4*)(gw);
        float4 w1 = *(const float4*)(gw + 4);
        float sc = scl[lrow];
        ushort_t ta[8] = {f2b(a0.x*sc*w0.x), f2b(a0.y*sc*w0.y), f2b(a0.z*sc*w0.z), f2b(a0.w*sc*w0.w),
                          f2b(a1.x*sc*w1.x), f2b(a1.y*sc*w1.y), f2b(a1.z*sc*w1.z), f2b(a1.w*sc*w1.w)};
        areg = *(short8*)ta;
        breg = *(const float4*)(B + (size_t)(n0 + lrow) * DIN + kk + lc8);
    };
    auto sstore = [&](int buf){
        *(short8*)&As[buf][lrow][lc8] = areg;
        *(float4*)&Bs[buf][lrow][lc8] = breg;
    };

    f32x4 acc[2][2];
    #pragma unroll
    for (int i = 0; i < 2; ++i)
        #pragma unroll
        for (int j = 0; j < 2; ++j) acc[i][j] = (f32x4){0.f,0.f,0.f,0.f};

    const int nk = 4;
    gload(kbase); sstore(0);
    __syncthreads();
    for (int kt = 0; kt < nk; ++kt){
        const int buf = kt & 1;
        if (kt + 1 < nk) gload(kbase + (kt + 1) * 32);
        short8 af[2], bfr[2];
        af[0]  = *(const short8*)&As[buf][wm + fro][fk];
        af[1]  = *(const short8*)&As[buf][wm + 16 + fro][fk];
        bfr[0] = *(const short8*)&Bs[buf][wn + fro][fk];
        bfr[1] = *(const short8*)&Bs[buf][wn + 16 + fro][fk];
        #pragma unroll
        for (int i = 0; i < 2; ++i)
            #pragma unroll
            for (int j = 0; j < 2; ++j)
                acc[i][j] = __builtin_amdgcn_mfma_f32_16x16x32_bf16(af[i], bfr[j], acc[i][j], 0, 0, 0);
        if (kt + 1 < nk) sstore(buf ^ 1);
        __syncthreads();
    }
    float* Cp = part + (size_t)z * SLAB;
    #pragma unroll
    for (int i = 0; i < 2; ++i){
        #pragma unroll
        for (int j = 0; j < 2; ++j){
            int col = n0 + wn + j * 16 + (lane & 15);
            #pragma unroll
            for (int r = 0; r < 4; ++r){
                int row = m0 + wm + i * 16 + (lane >> 4) * 4 + r;
                Cp[(size_t)row * D + col] = acc[i][j][r];
            }
        }
    }
}

// ---------------- out reduce (layer 0 only): t += 0.5 * sum(8 partials)
__global__ void out_red_k(const float* __restrict__ part, float* __restrict__ t){
    int i = blockIdx.x * 256 + threadIdx.x;
    float v = 0.f;
    #pragma unroll
    for (int r = 0; r < 8; ++r) v += part[i + r * SLAB];
    t[i] += 0.5f * v;
}

// ---------------- final: teff = t + 0.5*sum(part), rmsnorm rows, partial mean
__global__ void finalmean_k(const float* __restrict__ T, const float* __restrict__ part,
                            const float* __restrict__ fw, float* __restrict__ tm8){
    __shared__ float sm4[4];
    int b = blockIdx.x, q = blockIdx.y;
    int d = threadIdx.x;
    float a = 0.f;
    for (int r = 0; r < 8; ++r){
        int row = b * 64 + q * 8 + r;
        size_t o = (size_t)row * D + d;
        float pv = 0.f;
        #pragma unroll
        for (int u = 0; u < 8; ++u) pv += part[o + (size_t)u * SLAB];
        float v = T[o] + 0.5f * pv;
        float ssl = v * v;
        #pragma unroll
        for (int off = 32; off > 0; off >>= 1) ssl += __shfl_down(ssl, off);
        if ((threadIdx.x & 63) == 0) sm4[threadIdx.x >> 6] = ssl;
        __syncthreads();
        float ss = sm4[0] + sm4[1] + sm4[2] + sm4[3];
        __syncthreads();
        float sc = rsqrtf(ss / (float)D + EPS);
        a += v * sc;
    }
    tm8[(q * BATCH + b) * D + d] = a * (1.f / (float)L) * fw[d];
}

// ---------------- head: single kernel, K=256, tm8 slabs summed in LDS, +bias
__global__ void head_k(const float* __restrict__ tm8, const float* __restrict__ hw,
                       const float* __restrict__ hb, float* __restrict__ out){
    __shared__ float trs[2][256];
    int i0 = blockIdx.x * 256;
    int mmin = i0 / NCLS;
    int t = threadIdx.x;
    #pragma unroll
    for (int mm = 0; mm < 2; ++mm){
        int m = mmin + mm;
        float v = 0.f;
        if (m < BATCH){
            #pragma unroll
            for (int q = 0; q < 8; ++q)
                v += tm8[(q * BATCH + m) * D + t];
        }
        trs[mm][t] = v;
    }
    __syncthreads();
    int i = i0 + t;
    if (i >= BATCH * NCLS) return;
    int m = i / NCLS, n = i - m * NCLS;
    const float* tr = trs[m - mmin];
    const float* hc = hw + n;
    float a0 = 0.f, a1 = 0.f, a2 = 0.f, a3 = 0.f;
    #pragma unroll 4
    for (int k = 0; k < D; k += 4){
        a0 = fmaf(tr[k],     hc[(size_t)k * NCLS],       a0);
        a1 = fmaf(tr[k + 1], hc[(size_t)(k + 1) * NCLS], a1);
        a2 = fmaf(tr[k + 2], hc[(size_t)(k + 2) * NCLS], a2);
        a3 = fmaf(tr[k + 3], hc[(size_t)(k + 3) * NCLS], a3);
    }
    out[i] = (a0 + a1) + (a2 + a3) + hb[n];
}

extern "C" void kernel_launch(void* const* d_in, const int* in_sizes, int n_in,
                              void* d_out, int out_size, void* d_ws, size_t ws_size,
                              hipStream_t stream){
    (void)in_sizes; (void)n_in; (void)out_size; (void)ws_size;
    const float* x       = (const float*)d_in[0];
    const float* patch_w = (const float*)d_in[1];
    const float* patch_b = (const float*)d_in[2];
    const float* pos     = (const float*)d_in[3];
    const float* norms_w = (const float*)d_in[4];
    const float* final_w = (const float*)d_in[5];
    const float* head_w  = (const float*)d_in[6];
    const float* head_b  = (const float*)d_in[7];
    const float* Win[2]  = {(const float*)d_in[8],  (const float*)d_in[16]};
    const float* cw[2]   = {(const float*)d_in[9],  (const float*)d_in[17]};
    const float* cb[2]   = {(const float*)d_in[10], (const float*)d_in[18]};
    const float* dtb[2]  = {(const float*)d_in[11], (const float*)d_in[19]};
    const float* Alog[2] = {(const float*)d_in[12], (const float*)d_in[20]};
    const float* Dp[2]   = {(const float*)d_in[13], (const float*)d_in[21]};
    const float* gn[2]   = {(const float*)d_in[14], (const float*)d_in[22]};
    const float* Wout[2] = {(const float*)d_in[15], (const float*)d_in[23]};

    float* ws = (float*)d_ws;
    float* t     = ws;                   // 262144
    float* tm8   = t     + 262144;       // 32768
    float* zb0   = tm8   + 32768;        // 524288
    float* zb1   = zb0   + 524288;
    float* xy0   = zb1   + 524288;       // 524288 (xs)
    float* xy1   = xy0   + 524288;
    float* gb0   = xy1   + 524288;       // 524288 (gate output)
    float* gb1   = gb0   + 524288;
    float* bc0   = gb1   + 524288;       // 131072
    float* bc1   = bc0   + 131072;
    float* dts0  = bc1   + 131072;       // 8192 x6
    float* dts1  = dts0  + 8192;
    float* cum0  = dts1  + 8192;
    float* cum1  = cum0  + 8192;
    float* ssq0  = cum1  + 8192;
    float* ssq1  = ssq0  + 8192;
    float* partP = ssq1  + 8192;         // 2097152
    float* partO = partP + 2097152;      // 2097152
    float* f32end = partO + 2097152;

    ushort_t* wbuf = (ushort_t*)f32end;          // 1712128
    ushort_t* win_bf  = wbuf;                    // 4 x 296960
    ushort_t* wout_bf = wbuf + 1187840;          // 4 x 131072

    const int BL = BATCH * L;   // 1024

    wconv_patch_k<<<2208, 256, 0, stream>>>(
        Win[0], Win[1], Wout[0], Wout[1], wbuf, x, patch_w, partP);
    patch_red_k<<<BL, 256, 0, stream>>>(partP, patch_b, pos, t);

    for (int i = 0; i < DEPTH; ++i){
        const float* cw0  = cw[0]   + (size_t)i * CDIM * DCONV;
        const float* cw1  = cw[1]   + (size_t)i * CDIM * DCONV;
        const float* cb0  = cb[0]   + (size_t)i * CDIM;
        const float* cb1  = cb[1]   + (size_t)i * CDIM;
        const float* dtb0 = dtb[0]  + (size_t)i * H;
        const float* dtb1 = dtb[1]  + (size_t)i * H;
        const float* Al0  = Alog[0] + (size_t)i * H;
        const float* Al1  = Alog[1] + (size_t)i * H;
        const float* Dp0  = Dp[0]   + (size_t)i * H;
        const float* Dp1  = Dp[1]   + (size_t)i * H;
        const float* gn0  = gn[0]   + (size_t)i * DIN;
        const float* gn1  = gn[1]   + (size_t)i * DIN;
        const ushort_t* Wi0 = win_bf  + (size_t)(2 * i + 0) * 296960;
        const ushort_t* Wi1 = win_bf  + (size_t)(2 * i + 1) * 296960;
        const ushort_t* Wo0 = wout_bf + (size_t)(2 * i + 0) * 131072;
        const ushort_t* Wo1 = wout_bf + (size_t)(2 * i + 1) * 131072;

        gemm_in_k<<<dim3(19, 16, 2), 256, 0, stream>>>(
            t, norms_w + i * D, Wi0, Wi1, cw0, cw1, cb0, cb1, dtb0, dtb1,
            Al0, Al1, zb0, zb1, xy0, xy1, bc0, bc1, dts0, dts1, cum0, cum1);
        yscan3_k<<<dim3(H, BATCH, 4), 512, 0, stream>>>(
            bc0, bc1, dts0, dts1, cum0, cum1, Dp0, Dp1, zb0, zb1,
            xy0, xy1, gb0, gb1, ssq0, ssq1);
        gemm_out_k<<<dim3(4, 16, 8), 256, 0, stream>>>(
            gb0, gb1, ssq0, ssq1, gn0, gn1, Wo0, Wo1, partO);
        if (i == 0)
            out_red_k<<<BL, 256, 0, stream>>>(partO, t);
    }

    finalmean_k<<<dim3(BATCH, 8), 256, 0, stream>>>(t, partO, final_w, tm8);
    head_k<<<(BATCH * NCLS + 255) / 256, 256, 0, stream>>>(
        tm8, head_w, head_b, (float*)d_out);
}